// Round 10
// baseline (190.192 us; speedup 1.0000x reference)
//
#include <hip/hip_runtime.h>

// Problem constants: B=2, S=4096, H=8, DH=64, D=512, M = B*S = 8192.
#define LOG2E 1.44269504088896340736f

typedef unsigned short u16;
typedef __bf16 bf16x4_t __attribute__((ext_vector_type(4)));
typedef __bf16 bf16x8_t __attribute__((ext_vector_type(8)));
typedef float f32x4_t __attribute__((ext_vector_type(4)));

__device__ __forceinline__ f32x4_t mfma16(bf16x8_t a, bf16x8_t b, f32x4_t c) {
  return __builtin_amdgcn_mfma_f32_16x16x32_bf16(a, b, c, 0, 0, 0);
}

// async 16B global -> LDS (dest = wave-uniform base + lane*16)
__device__ __forceinline__ void gl_lds16(const u16* g, u16* l) {
  __builtin_amdgcn_global_load_lds(
      (const __attribute__((address_space(1))) unsigned int*)g,
      (__attribute__((address_space(3))) unsigned int*)l, 16, 0, 0);
}

// convert 8 fp32 (two f32x4) -> 8 bf16, scaled, store 16B to LDS
__device__ __forceinline__ void cvt_store(u16* dst, f32x4_t a, f32x4_t b, float scale) {
  a *= scale; b *= scale;
  union { uint4 u; struct { bf16x4_t lo, hi; } s; } c;
  c.s.lo = __builtin_convertvector(a, bf16x4_t);
  c.s.hi = __builtin_convertvector(b, bf16x4_t);
  *(uint4*)dst = c.u;
}

// ---------------- fused projection kernel ----------------
// grid (128, 4): tokBase = x*64, featBase = y*128. Block 256 (4 waves, 2x2).
// Phase QK: C[64 tok x 128 feat] for Q and K simultaneously (A = X staged once).
// Phase V:  C[128 feat x 64 tok] = Wv @ X^T  (X rows L2-hot from phase QK).
// All outputs stored coalesced via LDS-transpose epilogues.
__global__ __launch_bounds__(256, 2) void proj_kernel(
    const float* __restrict__ X, const float* __restrict__ Wq,
    const float* __restrict__ Wk, const float* __restrict__ Wv,
    u16* __restrict__ Q, u16* __restrict__ K, u16* __restrict__ Vt) {
  __shared__ __align__(16) union {
    struct { u16 A[64 * 40]; u16 Bq[128 * 40]; u16 Bk[128 * 40]; } qk;  // 25 KB
    struct { u16 Av[128 * 40]; u16 Bx[64 * 40]; } v;                    // 15 KB
    u16 T2[64 * 136];   // QK transpose: [token][feature+pad] 17 KB
    u16 T[128 * 72];    // V transpose: [feature][token+pad] 18 KB
  } sh;

  const int t = threadIdx.x;
  const int wave = t >> 6, lane = t & 63;
  const int r = lane & 15, qd = lane >> 4;
  const int hm = wave & 1, wn = wave >> 1;
  const int tokBase = blockIdx.x * 64;
  const int featBase = blockIdx.y * 128;
  const int lr = t >> 2;          // 0..63
  const int lc = (t & 3) * 8;     // 0/8/16/24

  // ================= Phase QK =================
  const float* pA  = X  + (tokBase + lr) * 512 + lc;
  const float* pq0 = Wq + (featBase + lr) * 512 + lc;
  const float* pq1 = Wq + (featBase + 64 + lr) * 512 + lc;
  const float* pk0 = Wk + (featBase + lr) * 512 + lc;
  const float* pk1 = Wk + (featBase + 64 + lr) * 512 + lc;

  f32x4_t rA[2], rq0[2], rq1[2], rk0[2], rk1[2];
  rA[0]  = *(const f32x4_t*)(pA);  rA[1]  = *(const f32x4_t*)(pA + 4);
  rq0[0] = *(const f32x4_t*)(pq0); rq0[1] = *(const f32x4_t*)(pq0 + 4);
  rq1[0] = *(const f32x4_t*)(pq1); rq1[1] = *(const f32x4_t*)(pq1 + 4);
  rk0[0] = *(const f32x4_t*)(pk0); rk0[1] = *(const f32x4_t*)(pk0 + 4);
  rk1[0] = *(const f32x4_t*)(pk1); rk1[1] = *(const f32x4_t*)(pk1 + 4);

  f32x4_t accq[2][4], acck[2][4];
#pragma unroll
  for (int i = 0; i < 2; i++)
#pragma unroll
    for (int j = 0; j < 4; j++) {
      f32x4_t z = {0.f, 0.f, 0.f, 0.f};
      accq[i][j] = z; acck[i][j] = z;
    }

  const float qsc = 0.125f * LOG2E;
  for (int k0 = 0; k0 < 512; k0 += 32) {
    cvt_store(&sh.qk.A[lr * 40 + lc],         rA[0],  rA[1],  1.f);
    cvt_store(&sh.qk.Bq[lr * 40 + lc],        rq0[0], rq0[1], qsc);
    cvt_store(&sh.qk.Bq[(64 + lr) * 40 + lc], rq1[0], rq1[1], qsc);
    cvt_store(&sh.qk.Bk[lr * 40 + lc],        rk0[0], rk0[1], 1.f);
    cvt_store(&sh.qk.Bk[(64 + lr) * 40 + lc], rk1[0], rk1[1], 1.f);
    __syncthreads();
    if (k0 < 480) {
      rA[0]  = *(const f32x4_t*)(pA  + k0 + 32); rA[1]  = *(const f32x4_t*)(pA  + k0 + 36);
      rq0[0] = *(const f32x4_t*)(pq0 + k0 + 32); rq0[1] = *(const f32x4_t*)(pq0 + k0 + 36);
      rq1[0] = *(const f32x4_t*)(pq1 + k0 + 32); rq1[1] = *(const f32x4_t*)(pq1 + k0 + 36);
      rk0[0] = *(const f32x4_t*)(pk0 + k0 + 32); rk0[1] = *(const f32x4_t*)(pk0 + k0 + 36);
      rk1[0] = *(const f32x4_t*)(pk1 + k0 + 32); rk1[1] = *(const f32x4_t*)(pk1 + k0 + 36);
    }
    bf16x8_t af[2], bq[4], bk[4];
#pragma unroll
    for (int i = 0; i < 2; i++) af[i] = *(const bf16x8_t*)&sh.qk.A[(hm * 32 + i * 16 + r) * 40 + qd * 8];
#pragma unroll
    for (int j = 0; j < 4; j++) {
      bq[j] = *(const bf16x8_t*)&sh.qk.Bq[(wn * 64 + j * 16 + r) * 40 + qd * 8];
      bk[j] = *(const bf16x8_t*)&sh.qk.Bk[(wn * 64 + j * 16 + r) * 40 + qd * 8];
    }
#pragma unroll
    for (int i = 0; i < 2; i++)
#pragma unroll
      for (int j = 0; j < 4; j++) {
        accq[i][j] = mfma16(af[i], bq[j], accq[i][j]);
        acck[i][j] = mfma16(af[i], bk[j], acck[i][j]);
      }
    __syncthreads();
  }

  // ---- prefetch V-phase tile 0 into registers (latency hides under epilogues) ----
  const float* pv0 = Wv + (featBase + lr) * 512 + lc;
  const float* pv1 = Wv + (featBase + 64 + lr) * 512 + lc;
  f32x4_t rv0[2], rv1[2], rx[2];
  rv0[0] = *(const f32x4_t*)(pv0); rv0[1] = *(const f32x4_t*)(pv0 + 4);
  rv1[0] = *(const f32x4_t*)(pv1); rv1[1] = *(const f32x4_t*)(pv1 + 4);
  rx[0]  = *(const f32x4_t*)(pA);  rx[1]  = *(const f32x4_t*)(pA + 4);

  // ---- Q epilogue: LDS transpose -> coalesced b128 stores ----
#pragma unroll
  for (int i = 0; i < 2; i++)
#pragma unroll
    for (int j = 0; j < 4; j++)
#pragma unroll
      for (int reg = 0; reg < 4; reg++)
        *(__bf16*)&sh.T2[(hm * 32 + i * 16 + qd * 4 + reg) * 136 + wn * 64 + j * 16 + r] =
            (__bf16)accq[i][j][reg];
  __syncthreads();
#pragma unroll
  for (int rd = 0; rd < 4; rd++) {
    int row = (t >> 4) + rd * 16;
    int c = (t & 15) * 8;
    uint4 val = *(const uint4*)&sh.T2[row * 136 + c];
    *(uint4*)&Q[(long)(tokBase + row) * 512 + featBase + c] = val;
  }
  __syncthreads();

  // ---- K epilogue ----
#pragma unroll
  for (int i = 0; i < 2; i++)
#pragma unroll
    for (int j = 0; j < 4; j++)
#pragma unroll
      for (int reg = 0; reg < 4; reg++)
        *(__bf16*)&sh.T2[(hm * 32 + i * 16 + qd * 4 + reg) * 136 + wn * 64 + j * 16 + r] =
            (__bf16)acck[i][j][reg];
  __syncthreads();
#pragma unroll
  for (int rd = 0; rd < 4; rd++) {
    int row = (t >> 4) + rd * 16;
    int c = (t & 15) * 8;
    uint4 val = *(const uint4*)&sh.T2[row * 136 + c];
    *(uint4*)&K[(long)(tokBase + row) * 512 + featBase + c] = val;
  }
  __syncthreads();

  // ================= Phase V: V^T = Wv @ X^T =================
  f32x4_t accv[4][2];
#pragma unroll
  for (int i = 0; i < 4; i++)
#pragma unroll
    for (int j = 0; j < 2; j++) { f32x4_t z = {0.f, 0.f, 0.f, 0.f}; accv[i][j] = z; }

  for (int k0 = 0; k0 < 512; k0 += 32) {
    cvt_store(&sh.v.Av[lr * 40 + lc],         rv0[0], rv0[1], 1.f);
    cvt_store(&sh.v.Av[(64 + lr) * 40 + lc],  rv1[0], rv1[1], 1.f);
    cvt_store(&sh.v.Bx[lr * 40 + lc],         rx[0],  rx[1],  1.f);
    __syncthreads();
    if (k0 < 480) {
      rv0[0] = *(const f32x4_t*)(pv0 + k0 + 32); rv0[1] = *(const f32x4_t*)(pv0 + k0 + 36);
      rv1[0] = *(const f32x4_t*)(pv1 + k0 + 32); rv1[1] = *(const f32x4_t*)(pv1 + k0 + 36);
      rx[0]  = *(const f32x4_t*)(pA  + k0 + 32); rx[1]  = *(const f32x4_t*)(pA  + k0 + 36);
    }
    bf16x8_t av[4], bx[2];
#pragma unroll
    for (int i = 0; i < 4; i++) av[i] = *(const bf16x8_t*)&sh.v.Av[(hm * 64 + i * 16 + r) * 40 + qd * 8];
#pragma unroll
    for (int j = 0; j < 2; j++) bx[j] = *(const bf16x8_t*)&sh.v.Bx[(wn * 32 + j * 16 + r) * 40 + qd * 8];
#pragma unroll
    for (int i = 0; i < 4; i++)
#pragma unroll
      for (int j = 0; j < 2; j++) accv[i][j] = mfma16(av[i], bx[j], accv[i][j]);
    __syncthreads();
  }

  // ---- V^T epilogue: LDS transpose -> coalesced b128 stores ----
#pragma unroll
  for (int i = 0; i < 4; i++)
#pragma unroll
    for (int j = 0; j < 2; j++)
#pragma unroll
      for (int reg = 0; reg < 4; reg++)
        *(__bf16*)&sh.T[(hm * 64 + i * 16 + qd * 4 + reg) * 72 + wn * 32 + j * 16 + r] =
            (__bf16)accv[i][j][reg];
  __syncthreads();
  {
    const int bb = tokBase >> 12, ss = tokBase & 4095;
#pragma unroll
    for (int rd = 0; rd < 4; rd++) {
      int f = (t >> 3) + rd * 32;
      int c = (t & 7) * 8;
      uint4 val = *(const uint4*)&sh.T[f * 72 + c];
      *(uint4*)&Vt[((long)(bb * 512 + featBase + f)) * 4096 + ss + c] = val;
    }
  }
}

// ---------------- out-proj GEMM: Out[M,512] = Ab[M,512](bf16) @ Wo[512,512]^T(f32) + bo ----
__global__ __launch_bounds__(256) void gemm_out_kernel(
    const u16* __restrict__ Aat, const float* __restrict__ Wo,
    float* __restrict__ Out, const float* __restrict__ bo) {
  __shared__ __align__(16) u16 As[64][40];
  __shared__ __align__(16) u16 Bs[128][40];
  const int t = threadIdx.x;
  const int wave = t >> 6, lane = t & 63;
  const int r = lane & 15, qd = lane >> 4;
  const int wn = wave;
  const int Mbase = blockIdx.x * 64, Nbase = blockIdx.y * 128;
  const int lr = t >> 2;
  const int lc = (t & 3) * 8;

  f32x4_t acc[4][2];
#pragma unroll
  for (int i = 0; i < 4; i++)
#pragma unroll
    for (int j = 0; j < 2; j++) { f32x4_t z = {0.f, 0.f, 0.f, 0.f}; acc[i][j] = z; }

  const u16*   pa  = Aat + (Mbase + lr) * 512 + lc;
  const float* pb0 = Wo + (Nbase + lr) * 512 + lc;
  const float* pb1 = Wo + (Nbase + 64 + lr) * 512 + lc;

  uint4 ra = *(const uint4*)(pa);
  f32x4_t rb0[2], rb1[2];
  rb0[0] = *(const f32x4_t*)(pb0); rb0[1] = *(const f32x4_t*)(pb0 + 4);
  rb1[0] = *(const f32x4_t*)(pb1); rb1[1] = *(const f32x4_t*)(pb1 + 4);

  for (int k0 = 0; k0 < 512; k0 += 32) {
    *(uint4*)&As[lr][lc] = ra;
    cvt_store(&Bs[lr][lc],      rb0[0], rb0[1], 1.f);
    cvt_store(&Bs[64 + lr][lc], rb1[0], rb1[1], 1.f);
    __syncthreads();
    if (k0 < 480) {
      ra = *(const uint4*)(pa + k0 + 32);
      rb0[0] = *(const f32x4_t*)(pb0 + k0 + 32); rb0[1] = *(const f32x4_t*)(pb0 + k0 + 36);
      rb1[0] = *(const f32x4_t*)(pb1 + k0 + 32); rb1[1] = *(const f32x4_t*)(pb1 + k0 + 36);
    }
    bf16x8_t af[4], bfr[2];
#pragma unroll
    for (int i = 0; i < 4; i++) af[i]  = *(const bf16x8_t*)&As[i * 16 + r][qd * 8];
#pragma unroll
    for (int j = 0; j < 2; j++) bfr[j] = *(const bf16x8_t*)&Bs[wn * 32 + j * 16 + r][qd * 8];
#pragma unroll
    for (int i = 0; i < 4; i++)
#pragma unroll
      for (int j = 0; j < 2; j++) acc[i][j] = mfma16(af[i], bfr[j], acc[i][j]);
    __syncthreads();
  }

  float bv[2];
#pragma unroll
  for (int j = 0; j < 2; j++) bv[j] = bo[Nbase + wn * 32 + j * 16 + r];
#pragma unroll
  for (int i = 0; i < 4; i++)
#pragma unroll
    for (int reg = 0; reg < 4; reg++) {
      int gr = Mbase + i * 16 + qd * 4 + reg;
#pragma unroll
      for (int j = 0; j < 2; j++) {
        int gc = Nbase + wn * 32 + j * 16 + r;
        Out[gr * 512 + gc] = acc[i][j][reg] + bv[j];
      }
    }
}

// ---------------- flash attention v7 (unchanged): full-K PV via key relabeling ----
__global__ __launch_bounds__(256, 2) void attn_kernel(
    const u16* __restrict__ Q, const u16* __restrict__ K, const u16* __restrict__ Vt,
    u16* __restrict__ Oattn) {
  __shared__ __align__(16) u16 Ks[2][2][4096];
  __shared__ __align__(16) u16 Vs[2][2][4096];

  const int t = threadIdx.x;
  const int wave = t >> 6, lane = t & 63;
  const int r = lane & 15, qd = lane >> 4;
  const int g = wave & 1, kv = wave >> 1;
  const int bh = blockIdx.y;
  const int b = bh >> 3, h = bh & 7;
  const long bbase = (long)b * 4096 * 512;
  const int q0 = blockIdx.x * 128;

  const int sw = r & 7;
  const int ck0 = (qd ^ sw) * 8;
  const int ck1 = ((qd + 4) ^ sw) * 8;
  int vo0[2], vo1[2];
#pragma unroll
  for (int c = 0; c < 2; c++) {
    vo0[c] = ((c * 4 + (qd >> 1)) ^ sw) * 8 + 4 * (qd & 1);
    vo1[c] = ((c * 4 + 2 + (qd >> 1)) ^ sw) * 8 + 4 * (qd & 1);
  }

  bf16x8_t ones8;
#pragma unroll
  for (int j = 0; j < 8; j++) ones8[j] = (__bf16)1.0f;

  bf16x8_t qf[4][2];
#pragma unroll
  for (int qa = 0; qa < 4; qa++) {
    const u16* qp = Q + bbase + (long)(q0 + g * 64 + qa * 16 + r) * 512 + h * 64 + qd * 8;
    qf[qa][0] = *(const bf16x8_t*)(qp);
    qf[qa][1] = *(const bf16x8_t*)(qp + 32);
  }

  f32x4_t accO[4][4];
  f32x4_t accL[4];
#pragma unroll
  for (int qa = 0; qa < 4; qa++) {
    f32x4_t z = {0.f, 0.f, 0.f, 0.f};
    accL[qa] = z;
#pragma unroll
    for (int nt = 0; nt < 4; nt++) accO[qa][nt] = z;
  }

  const int rr = lane >> 3;
  const int cc = (lane & 7) ^ rr;
  const u16* kgb = K + bbase + (long)(kv * 2048 + g * 32 + rr) * 512 + h * 64 + cc * 8;
  const u16* vgb = Vt + ((long)(b * 512 + h * 64 + g * 32 + rr)) * 4096 + kv * 2048 + cc * 8;

#pragma unroll
  for (int i = 0; i < 4; i++) gl_lds16(kgb + (long)i * 8 * 512, &Ks[kv][0][g * 2048] + i * 512);
#pragma unroll
  for (int i = 0; i < 4; i++) gl_lds16(vgb + i * 8 * 4096, &Vs[kv][0][g * 2048] + i * 512);

  for (int it = 0; it < 32; it++) {
    const int buf = it & 1;
    __syncthreads();

    if (it < 31) {
      const int nb = (it + 1) & 1;
      const long ko = (long)(it + 1) * 64;
#pragma unroll
      for (int i = 0; i < 4; i++)
        gl_lds16(kgb + (ko + i * 8) * 512, &Ks[kv][nb][g * 2048] + i * 512);
#pragma unroll
      for (int i = 0; i < 4; i++)
        gl_lds16(vgb + ko + (long)i * 8 * 4096, &Vs[kv][nb][g * 2048] + i * 512);
    }

    bf16x8_t kf[4][2];
#pragma unroll
    for (int nt = 0; nt < 4; nt++) {
      const u16* kb = &Ks[kv][buf][(nt * 16 + r) * 64];
      kf[nt][0] = *(const bf16x8_t*)(kb + ck0);
      kf[nt][1] = *(const bf16x8_t*)(kb + ck1);
    }

    f32x4_t St[4][4];
#pragma unroll
    for (int qa = 0; qa < 4; qa++)
#pragma unroll
      for (int nt = 0; nt < 4; nt++) {
        f32x4_t z = {0.f, 0.f, 0.f, 0.f};
        z = mfma16(kf[nt][0], qf[qa][0], z);
        z = mfma16(kf[nt][1], qf[qa][1], z);
        St[qa][nt] = z;
      }

    bf16x8_t pf[4][2];
#pragma unroll
    for (int qa = 0; qa < 4; qa++)
#pragma unroll
      for (int c = 0; c < 2; c++) {
        f32x4_t e0, e1;
#pragma unroll
        for (int j = 0; j < 4; j++) {
          e0[j] = __builtin_amdgcn_exp2f(St[qa][2 * c][j]);
          e1[j] = __builtin_amdgcn_exp2f(St[qa][2 * c + 1][j]);
        }
        bf16x4_t b0 = __builtin_convertvector(e0, bf16x4_t);
        bf16x4_t b1 = __builtin_convertvector(e1, bf16x4_t);
        bf16x8_t p8;
#pragma unroll
        for (int j = 0; j < 4; j++) { p8[j] = b0[j]; p8[4 + j] = b1[j]; }
        pf[qa][c] = p8;
      }

#pragma unroll
    for (int qa = 0; qa < 4; qa++)
#pragma unroll
      for (int c = 0; c < 2; c++)
        accL[qa] = mfma16(ones8, pf[qa][c], accL[qa]);

#pragma unroll
    for (int c = 0; c < 2; c++) {
      bf16x8_t va[4];
#pragma unroll
      for (int dm = 0; dm < 4; dm++) {
        const u16* vb = &Vs[kv][buf][(dm * 16 + r) * 64];
        union { uint4 u; bf16x8_t v; } cat;
        *(uint2*)&cat.u.x = *(const uint2*)(vb + vo0[c]);
        *(uint2*)&cat.u.z = *(const uint2*)(vb + vo1[c]);
        va[dm] = cat.v;
      }
#pragma unroll
      for (int qa = 0; qa < 4; qa++)
#pragma unroll
        for (int dm = 0; dm < 4; dm++)
          accO[qa][dm] = mfma16(va[dm], pf[qa][c], accO[qa][dm]);
    }
  }

  __syncthreads();
  float* Sc  = (float*)&Ks[0][0][0];
  float* Lsc = (float*)&Vs[0][0][0];
  if (kv == 1) {
#pragma unroll
    for (int qa = 0; qa < 4; qa++) {
#pragma unroll
      for (int dm = 0; dm < 4; dm++)
        *(f32x4_t*)&Sc[g * 4096 + ((qa * 4 + dm) * 64 + lane) * 4] = accO[qa][dm];
      Lsc[g * 256 + qa * 64 + lane] = accL[qa][0];
    }
  }
  __syncthreads();
  if (kv == 0) {
#pragma unroll
    for (int qa = 0; qa < 4; qa++) {
      float L = accL[qa][0] + Lsc[g * 256 + qa * 64 + lane];
      float inv = 1.f / L;
      int gq = q0 + g * 64 + qa * 16 + r;
#pragma unroll
      for (int dm = 0; dm < 4; dm++) {
        f32x4_t o = *(const f32x4_t*)&Sc[g * 4096 + ((qa * 4 + dm) * 64 + lane) * 4];
        o += accO[qa][dm];
        bf16x4_t ob;
#pragma unroll
        for (int reg = 0; reg < 4; reg++) ob[reg] = (__bf16)(o[reg] * inv);
        *(uint2*)&Oattn[bbase + (long)gq * 512 + h * 64 + dm * 16 + qd * 4] = *(uint2*)&ob;
      }
    }
  }
}

// ---------------- launch ----------------
extern "C" void kernel_launch(void* const* d_in, const int* in_sizes, int n_in,
                              void* d_out, int out_size, void* d_ws, size_t ws_size,
                              hipStream_t stream) {
  const float* x  = (const float*)d_in[0];
  const float* Wq = (const float*)d_in[1];
  const float* Wk = (const float*)d_in[2];
  const float* Wv = (const float*)d_in[3];
  const float* Wo = (const float*)d_in[4];
  const float* bo = (const float*)d_in[5];
  float* out = (float*)d_out;

  u16* ws  = (u16*)d_ws;
  u16* Qb  = ws;
  u16* Kb  = Qb  + 4194304;
  u16* Vtg = Kb  + 4194304;   // V^T: [2*512][4096]
  u16* Ab  = Vtg + 4194304;

  dim3 g1(128, 4);
  proj_kernel<<<g1, 256, 0, stream>>>(x, Wq, Wk, Wv, Qb, Kb, Vtg);

  dim3 g2(32, 16);
  attn_kernel<<<g2, 256, 0, stream>>>(Qb, Kb, Vtg, Ab);

  dim3 g3(128, 4);
  gemm_out_kernel<<<g3, 256, 0, stream>>>(Ab, Wo, out, bo);
}